// Round 1
// baseline (5796.178 us; speedup 1.0000x reference)
//
#include <hip/hip_runtime.h>
#include <math.h>

#define T_DIM 64
#define B_DIM 32
#define A_DIM 8
#define N_ENT 16
#define M_SLOTS 33
#define DSELF 290
#define S_TOT 16384
#define BA 256

#define ACT_OFF 0
#define LP_OFF 32768
#define ENT_OFF 49152

__device__ __forceinline__ float sigf(float x) { return 1.0f / (1.0f + expf(-x)); }

// ---------------------------------------------------------------------------
// Kernel 1: per-agent-step front end (conv + entity MLPs + attention + pool)
// One block per agent-step s = ((t*B)+b)*A+a. 256 threads.
// ---------------------------------------------------------------------------
__global__ __launch_bounds__(256) void k_front(
    const float* __restrict__ x_agent, const float* __restrict__ x_lidar,
    const float* __restrict__ x_safe, const float* __restrict__ x_ent0,
    const float* __restrict__ x_ent1, const int* __restrict__ mask0,
    const int* __restrict__ mask1,
    const float* __restrict__ conv_w, const float* __restrict__ conv_b,
    const float* __restrict__ self_w, const float* __restrict__ self_b,
    const float* __restrict__ ent0_w, const float* __restrict__ ent0_b,
    const float* __restrict__ ent1_w, const float* __restrict__ ent1_b,
    const float* __restrict__ inp_w, const float* __restrict__ inp_b,
    const float* __restrict__ outp_w, const float* __restrict__ outp_b,
    const float* __restrict__ sa_w, const float* __restrict__ sa_b,
    const float* __restrict__ pool_w, const float* __restrict__ pool_b,
    float* __restrict__ zin)
{
    __shared__ float xs[DSELF];        // x_self (290)
    __shared__ float lid[32];
    __shared__ float e0[N_ENT * 12];
    __shared__ float e1[N_ENT * 8];
    __shared__ float msk[M_SLOTS];
    __shared__ float ze[M_SLOTS * 64]; // z_ent, later res
    __shared__ float qkv[M_SLOTS * 192]; // later reused as o2 (first 2112 floats)
    __shared__ float ol[M_SLOTS * 64];
    __shared__ float pooled[64];
    __shared__ float zin_x[128];       // pool_w xs-part precompute

    const int s = blockIdx.x;
    const int tid = threadIdx.x;

    // ---- P0: stage inputs ----
    if (tid < 32) lid[tid] = x_lidar[(size_t)s * 32 + tid];
    else if (tid < 48) xs[tid - 32] = x_agent[(size_t)s * 16 + (tid - 32)];
    else if (tid < 52) xs[286 + (tid - 48)] = x_safe[(size_t)s * 4 + (tid - 48)];
    if (tid >= 64 && tid < 80) msk[1 + (tid - 64)] = (float)mask0[(size_t)s * 16 + (tid - 64)];
    if (tid >= 80 && tid < 96) msk[17 + (tid - 80)] = (float)mask1[(size_t)s * 16 + (tid - 80)];
    if (tid == 63) msk[0] = 1.0f;
    for (int i = tid; i < N_ENT * 12; i += 256) e0[i] = x_ent0[(size_t)s * (N_ENT * 12) + i];
    for (int i = tid; i < N_ENT * 8; i += 256) e1[i] = x_ent1[(size_t)s * (N_ENT * 8) + i];
    __syncthreads();
    // conv1d: 9 out channels, k=3, VALID (30 positions), relu; layout c*30+p
    for (int i = tid; i < 270; i += 256) {
        int c = i / 30, p = i - c * 30;
        float v = conv_b[c] + conv_w[c * 3] * lid[p] + conv_w[c * 3 + 1] * lid[p + 1]
                + conv_w[c * 3 + 2] * lid[p + 2];
        xs[16 + i] = fmaxf(v, 0.0f);
    }
    __syncthreads();

    // ---- P1: entity MLPs (+ pool xs-part on group 3) ----
    const int lane = tid & 63;
    const int grp = tid >> 6;
    if (grp == 0) {
        // z_self: lin(concat[xs,xs], self_w) -> fold the two weight halves
        const float* w = self_w + lane * 580;
        float acc = self_b[lane];
        for (int d = 0; d < DSELF; ++d) acc = fmaf(w[d] + w[290 + d], xs[d], acc);
        ze[lane] = fmaxf(acc, 0.0f);
    } else if (grp == 1) {
        // z0[n] = relu(W_e . ent0[n] + W_x . xs + b); W_x.xs shared across n
        const float* w = ent0_w + lane * 302;
        float xp = ent0_b[lane];
        for (int d = 0; d < DSELF; ++d) xp = fmaf(w[12 + d], xs[d], xp);
        float acc[N_ENT];
        #pragma unroll
        for (int n = 0; n < N_ENT; ++n) acc[n] = xp;
        #pragma unroll
        for (int d = 0; d < 12; ++d) {
            float wv = w[d];
            #pragma unroll
            for (int n = 0; n < N_ENT; ++n) acc[n] = fmaf(wv, e0[n * 12 + d], acc[n]);
        }
        #pragma unroll
        for (int n = 0; n < N_ENT; ++n) ze[(1 + n) * 64 + lane] = fmaxf(acc[n], 0.0f);
    } else if (grp == 2) {
        const float* w = ent1_w + lane * 298;
        float xp = ent1_b[lane];
        for (int d = 0; d < DSELF; ++d) xp = fmaf(w[8 + d], xs[d], xp);
        float acc[N_ENT];
        #pragma unroll
        for (int n = 0; n < N_ENT; ++n) acc[n] = xp;
        #pragma unroll
        for (int d = 0; d < 8; ++d) {
            float wv = w[d];
            #pragma unroll
            for (int n = 0; n < N_ENT; ++n) acc[n] = fmaf(wv, e1[n * 8 + d], acc[n]);
        }
        #pragma unroll
        for (int n = 0; n < N_ENT; ++n) ze[(17 + n) * 64 + lane] = fmaxf(acc[n], 0.0f);
    } else {
        // pool_w xs-part: zin_x[r] = sum_d pool_w[r,d]*xs[d], rows lane, lane+64
        #pragma unroll
        for (int rr = 0; rr < 2; ++rr) {
            int r = lane + rr * 64;
            const float* w = pool_w + (size_t)r * 354;
            float acc = 0.0f;
            for (int d = 0; d < DSELF; ++d) acc = fmaf(w[d], xs[d], acc);
            zin_x[r] = acc;
        }
    }
    __syncthreads();

    // ---- P2: in_proj qkv = ze @ inp_w.T + b  (33 x 192) ----
    for (int idx = tid; idx < M_SLOTS * 192; idx += 256) {
        int m = idx / 192, r = idx - m * 192;
        const float* w = inp_w + r * 64;
        const float* z = ze + m * 64;
        float acc = inp_b[r];
        #pragma unroll 8
        for (int e = 0; e < 64; ++e) acc = fmaf(w[e], z[e], acc);
        qkv[idx] = acc;
    }
    __syncthreads();

    // ---- P3: attention, one (q,h) pair per thread (132 threads) ----
    if (tid < M_SLOTS * 4) {
        int qq = tid >> 2, h = tid & 3;
        const float* qrow = qkv + qq * 192 + h * 16;
        float sc[M_SLOTS];
        float mx = -3.0e38f;
        #pragma unroll
        for (int k = 0; k < M_SLOTS; ++k) {
            const float* krow = qkv + k * 192 + 64 + h * 16;
            float d0 = 0.0f;
            #pragma unroll
            for (int d = 0; d < 16; ++d) d0 = fmaf(qrow[d], krow[d], d0);
            float v = (msk[k] > 0.0f) ? d0 * 0.25f : -1.0e9f;
            sc[k] = v;
            mx = fmaxf(mx, v);
        }
        float sum = 0.0f;
        #pragma unroll
        for (int k = 0; k < M_SLOTS; ++k) { float e = expf(sc[k] - mx); sc[k] = e; sum += e; }
        float inv = 1.0f / sum;
        #pragma unroll
        for (int d = 0; d < 16; ++d) {
            float acc = 0.0f;
            #pragma unroll
            for (int k = 0; k < M_SLOTS; ++k)
                acc = fmaf(sc[k], qkv[k * 192 + 128 + h * 16 + d], acc);
            ol[qq * 64 + h * 16 + d] = acc * inv;
        }
    }
    __syncthreads();

    // ---- P4a: out_proj -> o2 (reuse qkv storage) ----
    for (int idx = tid; idx < M_SLOTS * 64; idx += 256) {
        int m = idx >> 6, e = idx & 63;
        const float* w = outp_w + e * 64;
        const float* orow = ol + m * 64;
        float acc = outp_b[e];
        #pragma unroll 8
        for (int f = 0; f < 64; ++f) acc = fmaf(w[f], orow[f], acc);
        qkv[idx] = acc;
    }
    __syncthreads();
    // ---- P4b: res = ze + relu(sa(o2)) in place ----
    for (int idx = tid; idx < M_SLOTS * 64; idx += 256) {
        int m = idx >> 6, e = idx & 63;
        const float* w = sa_w + e * 64;
        const float* o2 = qkv + m * 64;
        float acc = sa_b[e];
        #pragma unroll 8
        for (int f = 0; f < 64; ++f) acc = fmaf(w[f], o2[f], acc);
        ze[idx] = ze[idx] + fmaxf(acc, 0.0f);
    }
    __syncthreads();
    // ---- P4c: masked mean pool over M (divide by 33) ----
    if (tid < 64) {
        float acc = 0.0f;
        #pragma unroll
        for (int m = 0; m < M_SLOTS; ++m) acc = fmaf(ze[m * 64 + tid], msk[m], acc);
        pooled[tid] = acc * (1.0f / 33.0f);
    }
    __syncthreads();
    // ---- P4d: zin = relu(pool_w @ [xs; pooled] + b) ----
    if (tid < 128) {
        const float* w = pool_w + (size_t)tid * 354 + 290;
        float acc = pool_b[tid] + zin_x[tid];
        #pragma unroll 8
        for (int e = 0; e < 64; ++e) acc = fmaf(w[e], pooled[e], acc);
        zin[(size_t)s * 128 + tid] = fmaxf(acc, 0.0f);
    }
}

// ---------------------------------------------------------------------------
// Kernel 2: LSTM scan. One block per sample (256 blocks), 512 threads.
// Thread r owns gate-row r of W_ih (phase 1) then W_hh (phase 2) in registers.
// x-parts for all 64 steps cached in LDS (128 KB).
// ---------------------------------------------------------------------------
__global__ __launch_bounds__(512) void k_lstm(
    const float* __restrict__ zin, const float* __restrict__ w_ih,
    const float* __restrict__ w_hh, const float* __restrict__ b_ih,
    const float* __restrict__ b_hh, const int* __restrict__ done,
    float* __restrict__ h_all)
{
    extern __shared__ float lds[];
    float* xp = lds;                 // 64*512
    float* zl = xp + 64 * 512;       // 128
    float* hl = zl + 128;            // 128
    float* gl = hl + 128;            // 512
    const int s = blockIdx.x;        // sample = b*8 + a
    const int r = threadIdx.x;       // gate row 0..511
    const int b = s >> 3;

    float4 w[32];
    {
        const float4* wsrc = (const float4*)(w_ih + (size_t)r * 128);
        #pragma unroll
        for (int j = 0; j < 32; ++j) w[j] = wsrc[j];
    }
    const float bias = b_ih[r] + b_hh[r];

    // Phase 1: xp[t][r] = bias + W_ih[r] . zin[t, s]
    for (int t = 0; t < T_DIM; ++t) {
        __syncthreads();
        if (r < 128) zl[r] = zin[((size_t)t * BA + s) * 128 + r];
        __syncthreads();
        const float4* x4 = (const float4*)zl;
        float a0 = 0.f, a1 = 0.f, a2 = 0.f, a3 = 0.f;
        #pragma unroll
        for (int j = 0; j < 32; ++j) {
            float4 wa = w[j], xa = x4[j];
            a0 = fmaf(wa.x, xa.x, a0);
            a1 = fmaf(wa.y, xa.y, a1);
            a2 = fmaf(wa.z, xa.z, a2);
            a3 = fmaf(wa.w, xa.w, a3);
        }
        xp[t * 512 + r] = bias + ((a0 + a1) + (a2 + a3));
    }

    // Phase 2: recurrent scan
    {
        const float4* wsrc = (const float4*)(w_hh + (size_t)r * 128);
        #pragma unroll
        for (int j = 0; j < 32; ++j) w[j] = wsrc[j];
    }
    if (r < 128) hl[r] = 0.0f;
    float c = 0.0f;
    __syncthreads();

    for (int t = 0; t < T_DIM; ++t) {
        const float4* h4 = (const float4*)hl;
        float a0 = 0.f, a1 = 0.f, a2 = 0.f, a3 = 0.f;
        #pragma unroll
        for (int j = 0; j < 32; ++j) {
            float4 wa = w[j], xa = h4[j];
            a0 = fmaf(wa.x, xa.x, a0);
            a1 = fmaf(wa.y, xa.y, a1);
            a2 = fmaf(wa.z, xa.z, a2);
            a3 = fmaf(wa.w, xa.w, a3);
        }
        gl[r] = xp[t * 512 + r] + ((a0 + a1) + (a2 + a3));
        __syncthreads();
        if (r < 128) {
            float keep = done[t * B_DIM + b] ? 0.0f : 1.0f;
            float gi = gl[r], gf = gl[r + 128], gg = gl[r + 256], go = gl[r + 384];
            c *= keep;  // hl already carries h*keep (folded below)
            c = sigf(gf) * c + sigf(gi) * tanhf(gg);
            float hn = sigf(go) * tanhf(c);
            // fold NEXT step's done-mask into the stored h
            float keepn = (t < T_DIM - 1) ? (done[(t + 1) * B_DIM + b] ? 0.0f : 1.0f) : 1.0f;
            hl[r] = hn * keepn;
            h_all[((size_t)t * BA + s) * 128 + r] = hn;
        }
        __syncthreads();
    }
}

// ---------------------------------------------------------------------------
// Kernel 3: categorical heads + actions passthrough
// ---------------------------------------------------------------------------
__global__ __launch_bounds__(256) void k_heads(
    const float* __restrict__ h_all, const int* __restrict__ actions,
    const float* __restrict__ h0w, const float* __restrict__ h0b,
    const float* __restrict__ h1w, const float* __restrict__ h1b,
    float* __restrict__ out)
{
    __shared__ float w0[640], w1[640], b0[8], b1[8];
    const int tid = threadIdx.x;
    for (int i = tid; i < 640; i += 256) { w0[i] = h0w[i]; w1[i] = h1w[i]; }
    if (tid < 5) { b0[tid] = h0b[tid]; b1[tid] = h1b[tid]; }
    __syncthreads();
    const int g = blockIdx.x * 256 + tid;   // flat (t,b,a) == (t*256 + sample)
    const float* h = h_all + (size_t)g * 128;
    float l0[5], l1[5];
    #pragma unroll
    for (int cc = 0; cc < 5; ++cc) { l0[cc] = b0[cc]; l1[cc] = b1[cc]; }
    for (int j = 0; j < 128; ++j) {
        float hv = h[j];
        #pragma unroll
        for (int cc = 0; cc < 5; ++cc) {
            l0[cc] = fmaf(w0[cc * 128 + j], hv, l0[cc]);
            l1[cc] = fmaf(w1[cc * 128 + j], hv, l1[cc]);
        }
    }
    int a0 = actions[(size_t)g * 2], a1 = actions[(size_t)g * 2 + 1];
    float m0 = l0[0], m1 = l1[0];
    #pragma unroll
    for (int cc = 1; cc < 5; ++cc) { m0 = fmaxf(m0, l0[cc]); m1 = fmaxf(m1, l1[cc]); }
    float s0 = 0.f, s1 = 0.f;
    #pragma unroll
    for (int cc = 0; cc < 5; ++cc) { s0 += expf(l0[cc] - m0); s1 += expf(l1[cc] - m1); }
    float lse0 = m0 + logf(s0), lse1 = m1 + logf(s1);
    float ent0 = 0.f, ent1 = 0.f, lp0 = 0.f, lp1 = 0.f;
    #pragma unroll
    for (int cc = 0; cc < 5; ++cc) {
        float p0 = l0[cc] - lse0, p1 = l1[cc] - lse1;
        ent0 -= expf(p0) * p0;
        ent1 -= expf(p1) * p1;
        if (cc == a0) lp0 = p0;
        if (cc == a1) lp1 = p1;
    }
    out[ACT_OFF + (size_t)g * 2]     = (float)a0;
    out[ACT_OFF + (size_t)g * 2 + 1] = (float)a1;
    out[LP_OFF + g]                  = lp0 * lp1;
    out[ENT_OFF + (size_t)g * 2]     = ent0;
    out[ENT_OFF + (size_t)g * 2 + 1] = ent1;
}

extern "C" void kernel_launch(void* const* d_in, const int* in_sizes, int n_in,
                              void* d_out, int out_size, void* d_ws, size_t ws_size,
                              hipStream_t stream)
{
    const float* x_agent = (const float*)d_in[0];
    const float* x_lidar = (const float*)d_in[1];
    const float* x_safe  = (const float*)d_in[2];
    const float* x_ent0  = (const float*)d_in[3];
    const float* x_ent1  = (const float*)d_in[4];
    const int*   mask0   = (const int*)d_in[5];
    const int*   mask1   = (const int*)d_in[6];
    const int*   done    = (const int*)d_in[7];
    const int*   actions = (const int*)d_in[8];
    const float* conv_w  = (const float*)d_in[9];
    const float* conv_b  = (const float*)d_in[10];
    const float* self_w  = (const float*)d_in[11];
    const float* self_b  = (const float*)d_in[12];
    const float* ent0_w  = (const float*)d_in[13];
    const float* ent0_b  = (const float*)d_in[14];
    const float* ent1_w  = (const float*)d_in[15];
    const float* ent1_b  = (const float*)d_in[16];
    const float* inp_w   = (const float*)d_in[17];
    const float* inp_b   = (const float*)d_in[18];
    const float* outp_w  = (const float*)d_in[19];
    const float* outp_b  = (const float*)d_in[20];
    const float* sa_w    = (const float*)d_in[21];
    const float* sa_b    = (const float*)d_in[22];
    const float* pool_w  = (const float*)d_in[23];
    const float* pool_b  = (const float*)d_in[24];
    const float* w_ih    = (const float*)d_in[25];
    const float* w_hh    = (const float*)d_in[26];
    const float* b_ih    = (const float*)d_in[27];
    const float* b_hh    = (const float*)d_in[28];
    const float* h0w     = (const float*)d_in[29];
    const float* h0b     = (const float*)d_in[30];
    const float* h1w     = (const float*)d_in[31];
    const float* h1b     = (const float*)d_in[32];

    float* zin   = (float*)d_ws;                 // S_TOT*128 floats (8.39 MB)
    float* h_all = zin + (size_t)S_TOT * 128;    // S_TOT*128 floats (8.39 MB)

    k_front<<<S_TOT, 256, 0, stream>>>(
        x_agent, x_lidar, x_safe, x_ent0, x_ent1, mask0, mask1,
        conv_w, conv_b, self_w, self_b, ent0_w, ent0_b, ent1_w, ent1_b,
        inp_w, inp_b, outp_w, outp_b, sa_w, sa_b, pool_w, pool_b, zin);

    size_t lstm_lds = (size_t)(64 * 512 + 128 + 128 + 512) * sizeof(float); // 134144 B
    k_lstm<<<BA, 512, lstm_lds, stream>>>(zin, w_ih, w_hh, b_ih, b_hh, done, h_all);

    k_heads<<<S_TOT / 256, 256, 0, stream>>>(h_all, actions, h0w, h0b, h1w, h1b, (float*)d_out);
}

// Round 2
// 2773.423 us; speedup vs baseline: 2.0899x; 2.0899x over previous
//
#include <hip/hip_runtime.h>
#include <hip/hip_bf16.h>
#include <math.h>

#define T_DIM 64
#define B_DIM 32
#define N_ENT 16
#define M_SLOTS 33
#define S_TOT 16384
#define BA 256
#define SB 64   // samples per block (front / attn kernels)

#define ACT_OFF 0
#define LP_OFF 32768
#define ENT_OFF 49152

__device__ __forceinline__ float sigf(float x) { return 1.0f / (1.0f + expf(-x)); }
__device__ __forceinline__ float bf2f(unsigned short u) {
    union { unsigned int i; float f; } a; a.i = ((unsigned int)u) << 16; return a.f;
}

// ---------------------------------------------------------------------------
// Kernel A: sample-batched front end. 256 blocks x 256 threads, 64 samples/blk.
// lane = sample; weight indices wave-uniform (scalar loads).
// Writes z_ent (bf16, [s][33][64]) and zin_x (f32, [s][128]).
// ---------------------------------------------------------------------------
__global__ __launch_bounds__(256, 1) void k_frontA(
    const float* __restrict__ xag, const float* __restrict__ xlid,
    const float* __restrict__ xsz, const float* __restrict__ xe0,
    const float* __restrict__ xe1,
    const float* __restrict__ conv_w, const float* __restrict__ conv_b,
    const float* __restrict__ self_w, const float* __restrict__ self_b,
    const float* __restrict__ ent0_w, const float* __restrict__ ent0_b,
    const float* __restrict__ ent1_w, const float* __restrict__ ent1_b,
    const float* __restrict__ pool_w,
    __hip_bfloat16* __restrict__ z_ent, float* __restrict__ zin_x)
{
    extern __shared__ float lds[];
    float* xs   = lds;              // [290][64] 18560
    float* ebuf = xs + 290 * 64;    // [192][66] 12672 (lid aliases start: [32][66])
    float* xp   = ebuf + 192 * 66;  // [64][65]  4160
    float* zbuf = xp + 64 * 65;     // [64][65]  4160   (total 39552 fl = 158208 B)

    const int tid = threadIdx.x;
    const int lane = tid & 63;
    const int wv = __builtin_amdgcn_readfirstlane(tid >> 6);
    const int s0 = blockIdx.x * SB;
    float* lid = ebuf; // [32][66]

    // ---- stage inputs (coalesced reads, transposed LDS writes) ----
    for (int i = tid; i < SB * 32; i += 256) {
        int d = i & 31, sl = i >> 5;
        lid[d * 66 + sl] = xlid[(size_t)s0 * 32 + i];
    }
    for (int i = tid; i < SB * 16; i += 256) {
        int d = i & 15, sl = i >> 4;
        xs[d * 64 + sl] = xag[(size_t)s0 * 16 + i];
    }
    for (int i = tid; i < SB * 4; i += 256) {
        int d = i & 3, sl = i >> 2;
        xs[(286 + d) * 64 + sl] = xsz[(size_t)s0 * 4 + i];
    }
    __syncthreads();
    // ---- conv1d (9ch, k=3, VALID->30) ----
    for (int cp = wv; cp < 270; cp += 4) {
        int c = cp / 30, p = cp - c * 30;
        float w0 = conv_w[c * 3], w1 = conv_w[c * 3 + 1], w2 = conv_w[c * 3 + 2];
        float v = conv_b[c] + w0 * lid[p * 66 + lane] + w1 * lid[(p + 1) * 66 + lane]
                + w2 * lid[(p + 2) * 66 + lane];
        xs[(16 + cp) * 64 + lane] = fmaxf(v, 0.0f);
    }
    __syncthreads();

    // ---- z_self (fold the duplicated 290-half) -> m = 0 ----
    for (int j = 0; j < 16; ++j) {
        int e = wv * 16 + j;
        const float* w = self_w + (size_t)e * 580;
        float acc = self_b[e];
        for (int d = 0; d < 290; ++d)
            acc = fmaf(w[d] + w[290 + d], xs[d * 64 + lane], acc);
        zbuf[e * 65 + lane] = fmaxf(acc, 0.0f);
    }
    __syncthreads();
    for (int i = tid; i < SB * 64; i += 256) {
        int e = i & 63, sl = i >> 6;
        z_ent[(size_t)(s0 + sl) * 2112 + e] = __float2bfloat16(zbuf[e * 65 + sl]);
    }
    __syncthreads();

    // ---- zin_x = pool_w[:, :290] @ xs  (two 64-row halves) ----
    for (int h = 0; h < 2; ++h) {
        for (int j = 0; j < 16; ++j) {
            int r = h * 64 + wv * 16 + j;
            const float* w = pool_w + (size_t)r * 354;
            float acc = 0.0f;
            for (int d = 0; d < 290; ++d) acc = fmaf(w[d], xs[d * 64 + lane], acc);
            zbuf[(r & 63) * 65 + lane] = acc;
        }
        __syncthreads();
        for (int i = tid; i < SB * 64; i += 256) {
            int e = i & 63, sl = i >> 6;
            zin_x[(size_t)(s0 + sl) * 128 + h * 64 + e] = zbuf[e * 65 + sl];
        }
        __syncthreads();
    }

    // ---- ent0: stage x_ent0, xp0 = W_x.xs + b, then 16 entity slots ----
    for (int i = tid; i < SB * 192; i += 256) {
        int sl = i / 192, d = i - sl * 192;
        ebuf[d * 66 + sl] = xe0[(size_t)s0 * 192 + i];
    }
    for (int j = 0; j < 16; ++j) {
        int e = wv * 16 + j;
        const float* w = ent0_w + (size_t)e * 302;
        float acc = ent0_b[e];
        for (int d = 0; d < 290; ++d) acc = fmaf(w[12 + d], xs[d * 64 + lane], acc);
        xp[e * 65 + lane] = acc;
    }
    __syncthreads();
    for (int n = 0; n < 16; ++n) {
        for (int j = 0; j < 16; ++j) {
            int e = wv * 16 + j;
            const float* w = ent0_w + (size_t)e * 302;
            float acc = xp[e * 65 + lane];
            #pragma unroll
            for (int dd = 0; dd < 12; ++dd)
                acc = fmaf(w[dd], ebuf[(n * 12 + dd) * 66 + lane], acc);
            zbuf[e * 65 + lane] = fmaxf(acc, 0.0f);
        }
        __syncthreads();
        for (int i = tid; i < SB * 64; i += 256) {
            int e = i & 63, sl = i >> 6;
            z_ent[(size_t)(s0 + sl) * 2112 + (1 + n) * 64 + e] = __float2bfloat16(zbuf[e * 65 + sl]);
        }
        __syncthreads();
    }

    // ---- ent1 ----
    for (int i = tid; i < SB * 128; i += 256) {
        int sl = i >> 7, d = i & 127;
        ebuf[d * 66 + sl] = xe1[(size_t)s0 * 128 + i];
    }
    for (int j = 0; j < 16; ++j) {
        int e = wv * 16 + j;
        const float* w = ent1_w + (size_t)e * 298;
        float acc = ent1_b[e];
        for (int d = 0; d < 290; ++d) acc = fmaf(w[8 + d], xs[d * 64 + lane], acc);
        xp[e * 65 + lane] = acc;
    }
    __syncthreads();
    for (int n = 0; n < 16; ++n) {
        for (int j = 0; j < 16; ++j) {
            int e = wv * 16 + j;
            const float* w = ent1_w + (size_t)e * 298;
            float acc = xp[e * 65 + lane];
            #pragma unroll
            for (int dd = 0; dd < 8; ++dd)
                acc = fmaf(w[dd], ebuf[(n * 8 + dd) * 66 + lane], acc);
            zbuf[e * 65 + lane] = fmaxf(acc, 0.0f);
        }
        __syncthreads();
        for (int i = tid; i < SB * 64; i += 256) {
            int e = i & 63, sl = i >> 6;
            z_ent[(size_t)(s0 + sl) * 2112 + (17 + n) * 64 + e] = __float2bfloat16(zbuf[e * 65 + sl]);
        }
        __syncthreads();
    }
}

// ---------------------------------------------------------------------------
// Kernel B: attention + pool + zin. 256 blocks x 256 threads; 64 samples
// processed serially per block. in_proj weights in registers; all other
// weights in LDS read as float4 broadcasts.
// ---------------------------------------------------------------------------
__global__ __launch_bounds__(256, 1) void k_attnB(
    const __hip_bfloat16* __restrict__ z_ent, const float* __restrict__ zin_x_ws,
    const int* __restrict__ mask0, const int* __restrict__ mask1,
    const float* __restrict__ inp_w, const float* __restrict__ inp_b,
    const float* __restrict__ outp_w, const float* __restrict__ outp_b,
    const float* __restrict__ sa_w, const float* __restrict__ sa_b,
    const float* __restrict__ pool_w, const float* __restrict__ pool_b,
    float* __restrict__ zin)
{
    extern __shared__ float lds[];
    float* qkv = lds;            // [33][196] 6468
    float* ze  = qkv + 6468;     // [33][64]  2112
    float* ol  = ze + 2112;      // [33][68]  2244
    float* o2  = ol + 2244;      // [33][68]  2244
    float* wot = o2 + 2244;      // [64][68]  4352 (out_proj^T)
    float* wst = wot + 4352;     // [64][68]  4352 (sa^T)
    float* bo  = wst + 4352;     // 64
    float* bs  = bo + 64;        // 64
    float* msk = bs + 64;        // 36 (pad)
    float* pooled = msk + 36;    // 64    total 22008 fl = 88032 B

    const int tid = threadIdx.x;
    const int s0 = blockIdx.x * SB;

    // ---- stage transposed weights + biases (once per block) ----
    for (int i = tid; i < 4096; i += 256) { int e = i >> 6, f = i & 63; wot[f * 68 + e] = outp_w[i]; }
    for (int i = tid; i < 4096; i += 256) { int e = i >> 6, f = i & 63; wst[f * 68 + e] = sa_w[i]; }
    if (tid < 64) { bo[tid] = outp_b[tid]; bs[tid] = sa_b[tid]; }

    // in_proj column in registers (thread r < 192)
    float wr[64]; float bq = 0.0f;
    if (tid < 192) {
        const float4* src = (const float4*)(inp_w + (size_t)tid * 64);
        #pragma unroll
        for (int q = 0; q < 16; ++q) {
            float4 v = src[q];
            wr[4 * q] = v.x; wr[4 * q + 1] = v.y; wr[4 * q + 2] = v.z; wr[4 * q + 3] = v.w;
        }
        bq = inp_b[tid];
    }
    // pool weight column in registers (thread r < 128)
    float wp[64]; float bp = 0.0f;
    if (tid < 128) {
        const float* src = pool_w + (size_t)tid * 354 + 290;
        #pragma unroll
        for (int e = 0; e < 64; ++e) wp[e] = src[e];
        bp = pool_b[tid];
    }
    __syncthreads();

    const int mq = tid >> 3;      // 0..31
    const int eo = tid & 7;       // 0..7 (8-wide e octet)

    for (int g = 0; g < SB; ++g) {
        const int s = s0 + g;
        // ---- stage ze (bf16 -> f32) + mask ----
        const unsigned int* zsrc = (const unsigned int*)(z_ent + (size_t)s * 2112);
        for (int i = tid; i < 1056; i += 256) {
            unsigned int v = zsrc[i];
            ze[2 * i]     = bf2f((unsigned short)(v & 0xffffu));
            ze[2 * i + 1] = bf2f((unsigned short)(v >> 16));
        }
        if (tid < 16) msk[1 + tid] = (float)mask0[(size_t)s * 16 + tid];
        else if (tid < 32) msk[17 + (tid - 16)] = (float)mask1[(size_t)s * 16 + (tid - 16)];
        else if (tid == 32) msk[0] = 1.0f;
        __syncthreads();

        // ---- in_proj: qkv[m][r] (192 threads, reg weights, f4 z broadcast) ----
        if (tid < 192) {
            for (int m = 0; m < 33; ++m) {
                const float4* z4 = (const float4*)(ze + m * 64);
                float p0 = 0.f, p1 = 0.f, p2 = 0.f, p3 = 0.f;
                #pragma unroll
                for (int q = 0; q < 16; ++q) {
                    float4 zv = z4[q];
                    p0 = fmaf(wr[4 * q],     zv.x, p0);
                    p1 = fmaf(wr[4 * q + 1], zv.y, p1);
                    p2 = fmaf(wr[4 * q + 2], zv.z, p2);
                    p3 = fmaf(wr[4 * q + 3], zv.w, p3);
                }
                qkv[m * 196 + tid] = bq + ((p0 + p1) + (p2 + p3));
            }
        }
        __syncthreads();

        // ---- attention (132 threads: qq 0..32, h 0..3) ----
        if (tid < 132) {
            int qq = tid >> 2, h = tid & 3;
            const float4* qk4 = (const float4*)qkv;
            float4 q0 = qk4[qq * 49 + h * 4], q1 = qk4[qq * 49 + h * 4 + 1];
            float4 q2 = qk4[qq * 49 + h * 4 + 2], q3 = qk4[qq * 49 + h * 4 + 3];
            float sc[33]; float mx = -3.0e38f;
            #pragma unroll
            for (int k = 0; k < 33; ++k) {
                float4 k0 = qk4[k * 49 + 16 + h * 4],     k1 = qk4[k * 49 + 16 + h * 4 + 1];
                float4 k2 = qk4[k * 49 + 16 + h * 4 + 2], k3 = qk4[k * 49 + 16 + h * 4 + 3];
                float d0 = q0.x * k0.x + q0.y * k0.y + q0.z * k0.z + q0.w * k0.w;
                d0 = fmaf(q1.x, k1.x, d0); d0 = fmaf(q1.y, k1.y, d0);
                d0 = fmaf(q1.z, k1.z, d0); d0 = fmaf(q1.w, k1.w, d0);
                d0 = fmaf(q2.x, k2.x, d0); d0 = fmaf(q2.y, k2.y, d0);
                d0 = fmaf(q2.z, k2.z, d0); d0 = fmaf(q2.w, k2.w, d0);
                d0 = fmaf(q3.x, k3.x, d0); d0 = fmaf(q3.y, k3.y, d0);
                d0 = fmaf(q3.z, k3.z, d0); d0 = fmaf(q3.w, k3.w, d0);
                float v = (msk[k] > 0.0f) ? d0 * 0.25f : -1.0e9f;
                sc[k] = v; mx = fmaxf(mx, v);
            }
            float sum = 0.0f;
            #pragma unroll
            for (int k = 0; k < 33; ++k) { float e = __expf(sc[k] - mx); sc[k] = e; sum += e; }
            float inv = 1.0f / sum;
            float4 a0 = {0,0,0,0}, a1 = {0,0,0,0}, a2 = {0,0,0,0}, a3 = {0,0,0,0};
            #pragma unroll
            for (int k = 0; k < 33; ++k) {
                float p = sc[k];
                float4 v0 = qk4[k * 49 + 32 + h * 4],     v1 = qk4[k * 49 + 32 + h * 4 + 1];
                float4 v2 = qk4[k * 49 + 32 + h * 4 + 2], v3 = qk4[k * 49 + 32 + h * 4 + 3];
                a0.x = fmaf(p, v0.x, a0.x); a0.y = fmaf(p, v0.y, a0.y);
                a0.z = fmaf(p, v0.z, a0.z); a0.w = fmaf(p, v0.w, a0.w);
                a1.x = fmaf(p, v1.x, a1.x); a1.y = fmaf(p, v1.y, a1.y);
                a1.z = fmaf(p, v1.z, a1.z); a1.w = fmaf(p, v1.w, a1.w);
                a2.x = fmaf(p, v2.x, a2.x); a2.y = fmaf(p, v2.y, a2.y);
                a2.z = fmaf(p, v2.z, a2.z); a2.w = fmaf(p, v2.w, a2.w);
                a3.x = fmaf(p, v3.x, a3.x); a3.y = fmaf(p, v3.y, a3.y);
                a3.z = fmaf(p, v3.z, a3.z); a3.w = fmaf(p, v3.w, a3.w);
            }
            float4* ol4 = (float4*)ol;
            a0.x *= inv; a0.y *= inv; a0.z *= inv; a0.w *= inv;
            a1.x *= inv; a1.y *= inv; a1.z *= inv; a1.w *= inv;
            a2.x *= inv; a2.y *= inv; a2.z *= inv; a2.w *= inv;
            a3.x *= inv; a3.y *= inv; a3.z *= inv; a3.w *= inv;
            ol4[qq * 17 + h * 4] = a0; ol4[qq * 17 + h * 4 + 1] = a1;
            ol4[qq * 17 + h * 4 + 2] = a2; ol4[qq * 17 + h * 4 + 3] = a3;
        }
        __syncthreads();

        // ---- out_proj: o2[m][e] (thread = (mq, eo): 8 e's, m += 32) ----
        {
            const float4* wo4 = (const float4*)wot;
            const float4* bo4 = (const float4*)bo;
            float4* o24 = (float4*)o2;
            for (int m = mq; m < 33; m += 32) {
                float4 a0 = bo4[eo * 2], a1 = bo4[eo * 2 + 1];
                for (int f = 0; f < 64; ++f) {
                    float ov = ol[m * 68 + f];
                    float4 w0 = wo4[f * 17 + eo * 2], w1 = wo4[f * 17 + eo * 2 + 1];
                    a0.x = fmaf(ov, w0.x, a0.x); a0.y = fmaf(ov, w0.y, a0.y);
                    a0.z = fmaf(ov, w0.z, a0.z); a0.w = fmaf(ov, w0.w, a0.w);
                    a1.x = fmaf(ov, w1.x, a1.x); a1.y = fmaf(ov, w1.y, a1.y);
                    a1.z = fmaf(ov, w1.z, a1.z); a1.w = fmaf(ov, w1.w, a1.w);
                }
                o24[m * 17 + eo * 2] = a0; o24[m * 17 + eo * 2 + 1] = a1;
            }
        }
        __syncthreads();

        // ---- sa + residual + mask -> res into ol ----
        {
            const float4* ws4 = (const float4*)wst;
            const float4* bs4 = (const float4*)bs;
            const float4* ze4 = (const float4*)ze;
            float4* ol4 = (float4*)ol;
            for (int m = mq; m < 33; m += 32) {
                float4 a0 = bs4[eo * 2], a1 = bs4[eo * 2 + 1];
                for (int f = 0; f < 64; ++f) {
                    float ov = o2[m * 68 + f];
                    float4 w0 = ws4[f * 17 + eo * 2], w1 = ws4[f * 17 + eo * 2 + 1];
                    a0.x = fmaf(ov, w0.x, a0.x); a0.y = fmaf(ov, w0.y, a0.y);
                    a0.z = fmaf(ov, w0.z, a0.z); a0.w = fmaf(ov, w0.w, a0.w);
                    a1.x = fmaf(ov, w1.x, a1.x); a1.y = fmaf(ov, w1.y, a1.y);
                    a1.z = fmaf(ov, w1.z, a1.z); a1.w = fmaf(ov, w1.w, a1.w);
                }
                float mk = msk[m];
                float4 z0 = ze4[m * 16 + eo * 2], z1 = ze4[m * 16 + eo * 2 + 1];
                float4 r0, r1;
                r0.x = mk * (z0.x + fmaxf(a0.x, 0.f)); r0.y = mk * (z0.y + fmaxf(a0.y, 0.f));
                r0.z = mk * (z0.z + fmaxf(a0.z, 0.f)); r0.w = mk * (z0.w + fmaxf(a0.w, 0.f));
                r1.x = mk * (z1.x + fmaxf(a1.x, 0.f)); r1.y = mk * (z1.y + fmaxf(a1.y, 0.f));
                r1.z = mk * (z1.z + fmaxf(a1.z, 0.f)); r1.w = mk * (z1.w + fmaxf(a1.w, 0.f));
                ol4[m * 17 + eo * 2] = r0; ol4[m * 17 + eo * 2 + 1] = r1;
            }
        }
        __syncthreads();

        // ---- pool ----
        if (tid < 64) {
            float acc = 0.0f;
            #pragma unroll
            for (int m = 0; m < 33; ++m) acc += ol[m * 68 + tid];
            pooled[tid] = acc * (1.0f / 33.0f);
        }
        __syncthreads();

        // ---- zin = relu(zin_x + wp . pooled + b) ----
        if (tid < 128) {
            const float4* p4 = (const float4*)pooled;
            float acc = bp + zin_x_ws[(size_t)s * 128 + tid];
            #pragma unroll
            for (int q = 0; q < 16; ++q) {
                float4 pv = p4[q];
                acc = fmaf(wp[4 * q], pv.x, acc);
                acc = fmaf(wp[4 * q + 1], pv.y, acc);
                acc = fmaf(wp[4 * q + 2], pv.z, acc);
                acc = fmaf(wp[4 * q + 3], pv.w, acc);
            }
            zin[(size_t)s * 128 + tid] = fmaxf(acc, 0.0f);
        }
        __syncthreads();
    }
}

// ---------------------------------------------------------------------------
// Kernel 2: LSTM scan (unchanged from round 1)
// ---------------------------------------------------------------------------
__global__ __launch_bounds__(512) void k_lstm(
    const float* __restrict__ zin, const float* __restrict__ w_ih,
    const float* __restrict__ w_hh, const float* __restrict__ b_ih,
    const float* __restrict__ b_hh, const int* __restrict__ done,
    float* __restrict__ h_all)
{
    extern __shared__ float lds[];
    float* xp = lds;
    float* zl = xp + 64 * 512;
    float* hl = zl + 128;
    float* gl = hl + 128;
    const int s = blockIdx.x;
    const int r = threadIdx.x;
    const int b = s >> 3;

    float4 w[32];
    {
        const float4* wsrc = (const float4*)(w_ih + (size_t)r * 128);
        #pragma unroll
        for (int j = 0; j < 32; ++j) w[j] = wsrc[j];
    }
    const float bias = b_ih[r] + b_hh[r];

    for (int t = 0; t < T_DIM; ++t) {
        __syncthreads();
        if (r < 128) zl[r] = zin[((size_t)t * BA + s) * 128 + r];
        __syncthreads();
        const float4* x4 = (const float4*)zl;
        float a0 = 0.f, a1 = 0.f, a2 = 0.f, a3 = 0.f;
        #pragma unroll
        for (int j = 0; j < 32; ++j) {
            float4 wa = w[j], xa = x4[j];
            a0 = fmaf(wa.x, xa.x, a0);
            a1 = fmaf(wa.y, xa.y, a1);
            a2 = fmaf(wa.z, xa.z, a2);
            a3 = fmaf(wa.w, xa.w, a3);
        }
        xp[t * 512 + r] = bias + ((a0 + a1) + (a2 + a3));
    }

    {
        const float4* wsrc = (const float4*)(w_hh + (size_t)r * 128);
        #pragma unroll
        for (int j = 0; j < 32; ++j) w[j] = wsrc[j];
    }
    if (r < 128) hl[r] = 0.0f;
    float c = 0.0f;
    __syncthreads();

    for (int t = 0; t < T_DIM; ++t) {
        const float4* h4 = (const float4*)hl;
        float a0 = 0.f, a1 = 0.f, a2 = 0.f, a3 = 0.f;
        #pragma unroll
        for (int j = 0; j < 32; ++j) {
            float4 wa = w[j], xa = h4[j];
            a0 = fmaf(wa.x, xa.x, a0);
            a1 = fmaf(wa.y, xa.y, a1);
            a2 = fmaf(wa.z, xa.z, a2);
            a3 = fmaf(wa.w, xa.w, a3);
        }
        gl[r] = xp[t * 512 + r] + ((a0 + a1) + (a2 + a3));
        __syncthreads();
        if (r < 128) {
            float keep = done[t * B_DIM + b] ? 0.0f : 1.0f;
            float gi = gl[r], gf = gl[r + 128], gg = gl[r + 256], go = gl[r + 384];
            c *= keep;
            c = sigf(gf) * c + sigf(gi) * tanhf(gg);
            float hn = sigf(go) * tanhf(c);
            float keepn = (t < T_DIM - 1) ? (done[(t + 1) * B_DIM + b] ? 0.0f : 1.0f) : 1.0f;
            hl[r] = hn * keepn;
            h_all[((size_t)t * BA + s) * 128 + r] = hn;
        }
        __syncthreads();
    }
}

// ---------------------------------------------------------------------------
// Kernel 3: categorical heads (unchanged)
// ---------------------------------------------------------------------------
__global__ __launch_bounds__(256) void k_heads(
    const float* __restrict__ h_all, const int* __restrict__ actions,
    const float* __restrict__ h0w, const float* __restrict__ h0b,
    const float* __restrict__ h1w, const float* __restrict__ h1b,
    float* __restrict__ out)
{
    __shared__ float w0[640], w1[640], b0[8], b1[8];
    const int tid = threadIdx.x;
    for (int i = tid; i < 640; i += 256) { w0[i] = h0w[i]; w1[i] = h1w[i]; }
    if (tid < 5) { b0[tid] = h0b[tid]; b1[tid] = h1b[tid]; }
    __syncthreads();
    const int g = blockIdx.x * 256 + tid;
    const float* h = h_all + (size_t)g * 128;
    float l0[5], l1[5];
    #pragma unroll
    for (int cc = 0; cc < 5; ++cc) { l0[cc] = b0[cc]; l1[cc] = b1[cc]; }
    for (int j = 0; j < 128; ++j) {
        float hv = h[j];
        #pragma unroll
        for (int cc = 0; cc < 5; ++cc) {
            l0[cc] = fmaf(w0[cc * 128 + j], hv, l0[cc]);
            l1[cc] = fmaf(w1[cc * 128 + j], hv, l1[cc]);
        }
    }
    int a0 = actions[(size_t)g * 2], a1 = actions[(size_t)g * 2 + 1];
    float m0 = l0[0], m1 = l1[0];
    #pragma unroll
    for (int cc = 1; cc < 5; ++cc) { m0 = fmaxf(m0, l0[cc]); m1 = fmaxf(m1, l1[cc]); }
    float s0 = 0.f, s1 = 0.f;
    #pragma unroll
    for (int cc = 0; cc < 5; ++cc) { s0 += expf(l0[cc] - m0); s1 += expf(l1[cc] - m1); }
    float lse0 = m0 + logf(s0), lse1 = m1 + logf(s1);
    float ent0 = 0.f, ent1 = 0.f, lp0 = 0.f, lp1 = 0.f;
    #pragma unroll
    for (int cc = 0; cc < 5; ++cc) {
        float p0 = l0[cc] - lse0, p1 = l1[cc] - lse1;
        ent0 -= expf(p0) * p0;
        ent1 -= expf(p1) * p1;
        if (cc == a0) lp0 = p0;
        if (cc == a1) lp1 = p1;
    }
    out[ACT_OFF + (size_t)g * 2]     = (float)a0;
    out[ACT_OFF + (size_t)g * 2 + 1] = (float)a1;
    out[LP_OFF + g]                  = lp0 * lp1;
    out[ENT_OFF + (size_t)g * 2]     = ent0;
    out[ENT_OFF + (size_t)g * 2 + 1] = ent1;
}

extern "C" void kernel_launch(void* const* d_in, const int* in_sizes, int n_in,
                              void* d_out, int out_size, void* d_ws, size_t ws_size,
                              hipStream_t stream)
{
    const float* x_agent = (const float*)d_in[0];
    const float* x_lidar = (const float*)d_in[1];
    const float* x_safe  = (const float*)d_in[2];
    const float* x_ent0  = (const float*)d_in[3];
    const float* x_ent1  = (const float*)d_in[4];
    const int*   mask0   = (const int*)d_in[5];
    const int*   mask1   = (const int*)d_in[6];
    const int*   done    = (const int*)d_in[7];
    const int*   actions = (const int*)d_in[8];
    const float* conv_w  = (const float*)d_in[9];
    const float* conv_b  = (const float*)d_in[10];
    const float* self_w  = (const float*)d_in[11];
    const float* self_b  = (const float*)d_in[12];
    const float* ent0_w  = (const float*)d_in[13];
    const float* ent0_b  = (const float*)d_in[14];
    const float* ent1_w  = (const float*)d_in[15];
    const float* ent1_b  = (const float*)d_in[16];
    const float* inp_w   = (const float*)d_in[17];
    const float* inp_b   = (const float*)d_in[18];
    const float* outp_w  = (const float*)d_in[19];
    const float* outp_b  = (const float*)d_in[20];
    const float* sa_w    = (const float*)d_in[21];
    const float* sa_b    = (const float*)d_in[22];
    const float* pool_w  = (const float*)d_in[23];
    const float* pool_b  = (const float*)d_in[24];
    const float* w_ih    = (const float*)d_in[25];
    const float* w_hh    = (const float*)d_in[26];
    const float* b_ih    = (const float*)d_in[27];
    const float* b_hh    = (const float*)d_in[28];
    const float* h0w     = (const float*)d_in[29];
    const float* h0b     = (const float*)d_in[30];
    const float* h1w     = (const float*)d_in[31];
    const float* h1b     = (const float*)d_in[32];

    // workspace: z_ent bf16 [16384][2112] (69.2MB) | zin_x | zin | h_all (f32, 8.39MB each)
    __hip_bfloat16* z_ent = (__hip_bfloat16*)d_ws;
    float* zin_x = (float*)((char*)d_ws + (size_t)S_TOT * 2112 * 2);
    float* zin   = zin_x + (size_t)S_TOT * 128;
    float* h_all = zin + (size_t)S_TOT * 128;

    size_t ldsA = (size_t)(290 * 64 + 192 * 66 + 64 * 65 + 64 * 65) * sizeof(float); // 158208
    k_frontA<<<S_TOT / SB, 256, ldsA, stream>>>(
        x_agent, x_lidar, x_safe, x_ent0, x_ent1,
        conv_w, conv_b, self_w, self_b, ent0_w, ent0_b, ent1_w, ent1_b,
        pool_w, z_ent, zin_x);

    size_t ldsB = (size_t)(6468 + 2112 + 2244 + 2244 + 4352 + 4352 + 64 + 64 + 36 + 64) * sizeof(float); // 88000
    k_attnB<<<S_TOT / SB, 256, ldsB, stream>>>(
        z_ent, zin_x, mask0, mask1, inp_w, inp_b, outp_w, outp_b,
        sa_w, sa_b, pool_w, pool_b, zin);

    size_t lstm_lds = (size_t)(64 * 512 + 128 + 128 + 512) * sizeof(float);
    k_lstm<<<BA, 512, lstm_lds, stream>>>(zin, w_ih, w_hh, b_ih, b_hh, done, h_all);

    k_heads<<<S_TOT / 256, 256, 0, stream>>>(h_all, actions, h0w, h0b, h1w, h1b, (float*)d_out);
}